// Round 1
// baseline (1301.885 us; speedup 1.0000x reference)
//
#include <hip/hip_runtime.h>
#include <math.h>
#include <stdint.h>

#define BB 64
#define SS 512
#define HH 1024
#define TT 21

// ---------------- Kernel 1: emissions = hs @ W^T + bias ----------------
// grid 256 x 512 threads. W (84KB) staged in LDS; wave handles 16 rows in
// groups of 4; 21 register accumulators per row; butterfly reduce over 64 lanes.
__global__ __launch_bounds__(512, 2) void k_emis(const float* __restrict__ hs,
                                                 const float* __restrict__ W,
                                                 const float* __restrict__ bias,
                                                 float* __restrict__ emis) {
  __shared__ float sW[TT * HH];  // 86016 B (gfx950: 160KB LDS/workgroup)
  for (int i = threadIdx.x; i < TT * HH; i += 512) sW[i] = W[i];
  __syncthreads();
  const int lane = threadIdx.x & 63;
  const int wid = threadIdx.x >> 6;
  const int gw = blockIdx.x * 8 + wid;  // 0..2047 waves, 16 rows each
  for (int rg = 0; rg < 4; ++rg) {
    const int row0 = gw * 16 + rg * 4;
    float4 h[4][4];
#pragma unroll
    for (int r = 0; r < 4; ++r) {
      const float4* hp = (const float4*)(hs + (size_t)(row0 + r) * HH);
#pragma unroll
      for (int c = 0; c < 4; ++c) h[r][c] = hp[c * 64 + lane];
    }
    float acc[4][TT];
#pragma unroll
    for (int r = 0; r < 4; ++r)
#pragma unroll
      for (int t = 0; t < TT; ++t) acc[r][t] = 0.f;
#pragma unroll
    for (int t = 0; t < TT; ++t) {
      const float4* wp = (const float4*)(sW + t * HH);
#pragma unroll
      for (int c = 0; c < 4; ++c) {
        float4 wv = wp[c * 64 + lane];
#pragma unroll
        for (int r = 0; r < 4; ++r) {
          acc[r][t] = fmaf(h[r][c].x, wv.x, acc[r][t]);
          acc[r][t] = fmaf(h[r][c].y, wv.y, acc[r][t]);
          acc[r][t] = fmaf(h[r][c].z, wv.z, acc[r][t]);
          acc[r][t] = fmaf(h[r][c].w, wv.w, acc[r][t]);
        }
      }
    }
#pragma unroll
    for (int r = 0; r < 4; ++r)
#pragma unroll
      for (int t = 0; t < TT; ++t) {
        float v = acc[r][t];
#pragma unroll
        for (int m = 1; m < 64; m <<= 1) v += __shfl_xor(v, m);
        acc[r][t] = v;
      }
    if (lane == 0) {
#pragma unroll
      for (int r = 0; r < 4; ++r) {
        float* ep = emis + (size_t)(row0 + r) * TT;
#pragma unroll
        for (int t = 0; t < TT; ++t) ep[t] = acc[r][t] + bias[t];
      }
    }
  }
}

// ---------------- Kernel 2: CRF forward scan + Viterbi ----------------
// grid 64 x 64 threads (1 wave). Blocks 0..31: CRF logsumexp scan in exp
// domain (2 batches/block, lanes 0-20 and 32-52). Blocks 32..63: Viterbi
// forward + backpointers in LDS + serial backtrace.
__global__ __launch_bounds__(64) void k_scan(const float* __restrict__ emis,
                                             const int* __restrict__ mask,
                                             const float* __restrict__ trans,
                                             const float* __restrict__ sv,
                                             const float* __restrict__ ev,
                                             float* __restrict__ logZ,
                                             float* __restrict__ pred) {
  const int lane = threadIdx.x;
  const int g = lane >> 5;
  const int j = lane & 31;
  const bool act = (j < TT);
  const int jj = act ? j : 0;
  const int src0 = g << 5;
  const int b = (blockIdx.x & 31) * 2 + g;
  const size_t eb = (size_t)b * SS * TT;

  if (blockIdx.x < 32) {
    // ---- CRF forward in exp domain: v = exp(alpha - C) ----
    float E[TT];
#pragma unroll
    for (int i = 0; i < TT; ++i) E[i] = expf(trans[i * TT + jj]);
    float v = act ? expf(sv[jj] + emis[eb + jj]) : 0.f;
    float C = 0.f;
    for (int t = 1; t < SS; ++t) {
      float e = emis[eb + (size_t)t * TT + jj];
      int mk = mask[b * SS + t];
      float q0 = 0.f, q1 = 0.f, q2 = 0.f;
#pragma unroll
      for (int i = 0; i < TT; i += 3) {
        q0 = fmaf(__shfl(v, src0 + i), E[i], q0);
        q1 = fmaf(__shfl(v, src0 + i + 1), E[i + 1], q1);
        q2 = fmaf(__shfl(v, src0 + i + 2), E[i + 2], q2);
      }
      float vn = (q0 + q1 + q2) * expf(e);
      v = (act && mk) ? vn : v;
      if ((t & 7) == 0) {
        // renorm by power of 2 of group max (exact; C compensates)
        float m = v;
#pragma unroll
        for (int d = 16; d >= 1; d >>= 1) m = fmaxf(m, __shfl_xor(m, d));
        int ex = (int)((__float_as_uint(m) >> 23) & 255u) - 127;
        v *= __uint_as_float((unsigned)(127 - ex) << 23);
        C += (float)ex * 0.6931471805599453f;
      }
    }
    float wv = act ? v * expf(ev[jj]) : 0.f;
#pragma unroll
    for (int d = 16; d >= 1; d >>= 1) wv += __shfl_xor(wv, d);
    if (j == 0) logZ[b] = C + logf(wv);
  } else {
    // ---- Viterbi forward + backtrace ----
    __shared__ unsigned char bp[2][SS][32];  // 32KB
    float Tc[TT];
#pragma unroll
    for (int i = 0; i < TT; ++i) Tc[i] = trans[i * TT + jj];
    float sc = act ? (sv[jj] + emis[eb + jj]) : -3.0e38f;
    for (int t = 1; t < SS; ++t) {
      float e = emis[eb + (size_t)t * TT + jj];
      int mk = mask[b * SS + t];
      float best = -3.0e38f;
      int bi = 0;
#pragma unroll
      for (int i = 0; i < TT; ++i) {
        float x = __shfl(sc, src0 + i) + Tc[i];
        bool cgt = (x > best);  // strict > : first index wins ties (matches argmax)
        best = cgt ? x : best;
        bi = cgt ? i : bi;
      }
      float ns = best + e;
      sc = (act && mk) ? ns : sc;
      bp[g][t][j] = (unsigned char)(mk ? bi : j);
    }
    __syncthreads();
    float fsv = act ? (sc + ev[jj]) : -3.0e38f;
    int idx = j;
#pragma unroll
    for (int d = 16; d >= 1; d >>= 1) {
      float ov = __shfl_xor(fsv, d);
      int oi = __shfl_xor(idx, d);
      bool take = (ov > fsv) || (ov == fsv && oi < idx);
      fsv = take ? ov : fsv;
      idx = take ? oi : idx;
    }
    if (j == 0) {
      int tag = idx;
      pred[b * SS + SS - 1] = (float)(mask[b * SS + SS - 1] ? tag : 0);
      for (int t = SS - 1; t >= 1; --t) {
        tag = bp[g][t][tag];
        pred[b * SS + t - 1] = (float)(mask[b * SS + t - 1] ? tag : 0);
      }
    }
  }
}

// ---------------- Kernel 3: numerator + loss reduction ----------------
__global__ __launch_bounds__(512) void k_loss(const float* __restrict__ emis,
                                              const int* __restrict__ mask,
                                              const int* __restrict__ labels,
                                              const float* __restrict__ trans,
                                              const float* __restrict__ sv,
                                              const float* __restrict__ ev,
                                              const float* __restrict__ logZ,
                                              float* __restrict__ outv) {
  __shared__ float red[512];
  const int tid = threadIdx.x;
  float p = 0.f;
  for (int bt = tid; bt < BB * (SS - 1); bt += 512) {
    const int b = bt / (SS - 1);
    const int t = bt - b * (SS - 1) + 1;
    const int lp = labels[b * SS + t - 1];
    const int lc = labels[b * SS + t];
    const float mk = (float)mask[b * SS + t];
    p += mk * (trans[lp * TT + lc] + emis[((size_t)b * SS + t) * TT + lc]);
  }
  if (tid < BB) {
    const int b = tid;
    const int l0 = labels[b * SS];
    p += sv[l0] + emis[((size_t)b * SS) * TT + l0];
    int cnt = 0;
    for (int s = 0; s < SS; ++s) cnt += (mask[b * SS + s] ? 1 : 0);
    const int lst = labels[b * SS + cnt - 1];
    p += ev[lst];
    p -= logZ[b];
  }
  red[tid] = p;
  __syncthreads();
  for (int s = 256; s > 0; s >>= 1) {
    if (tid < s) red[tid] += red[tid + s];
    __syncthreads();
  }
  if (tid == 0) outv[0] = -red[0];  // loss = -sum(numerator - logZ)
}

extern "C" void kernel_launch(void* const* d_in, const int* in_sizes, int n_in,
                              void* d_out, int out_size, void* d_ws, size_t ws_size,
                              hipStream_t stream) {
  const float* hs = (const float*)d_in[0];
  const int* msk = (const int*)d_in[1];
  const int* lab = (const int*)d_in[2];
  const float* W = (const float*)d_in[3];
  const float* bias = (const float*)d_in[4];
  const float* trans = (const float*)d_in[5];
  const float* sv = (const float*)d_in[6];
  const float* ev = (const float*)d_in[7];
  float* out = (float*)d_out;

  float* emis = (float*)d_ws;                       // 64*512*21 floats
  float* logZ = emis + (size_t)BB * SS * TT;        // 64 floats

  k_emis<<<256, 512, 0, stream>>>(hs, W, bias, emis);
  k_scan<<<64, 64, 0, stream>>>(emis, msk, trans, sv, ev, logZ, out + 1);
  k_loss<<<1, 512, 0, stream>>>(emis, msk, lab, trans, sv, ev, logZ, out);
}

// Round 2
// 1029.495 us; speedup vs baseline: 1.2646x; 1.2646x over previous
//
#include <hip/hip_runtime.h>
#include <math.h>
#include <stdint.h>

#define BB 64
#define SS 512
#define HH 1024
#define TT 21

// DPP-based partial reduce: v += lane[(i+N) mod 16 within row]
template <int CTRL>
__device__ __forceinline__ float dpp_add(float v) {
  int t = __builtin_amdgcn_update_dpp(0, __float_as_int(v), CTRL, 0xF, 0xF, true);
  return v + __int_as_float(t);
}
// full 64-lane sum, result in all lanes: 4 DPP row_ror adds + 2 cross shuffles
__device__ __forceinline__ float wave_sum(float v) {
  v = dpp_add<0x121>(v);  // row_ror:1
  v = dpp_add<0x122>(v);  // row_ror:2
  v = dpp_add<0x124>(v);  // row_ror:4
  v = dpp_add<0x128>(v);  // row_ror:8  -> full sum within each row of 16
  v += __shfl_xor(v, 16);
  v += __shfl_xor(v, 32);
  return v;
}

// ---------------- Kernel 1: emissions = hs @ W^T + bias ----------------
// 256 blocks x 1024 threads (16 waves). W (84KB) in LDS -> 1 block/CU,
// 16 waves/CU. Each wave: 8 rows as 4 groups of 2. acc[2][21]=42 VGPRs,
// h chunk 8 VGPRs -> ~70 VGPRs, no spills at the 128 cap.
__global__ __launch_bounds__(1024) void k_emis(const float* __restrict__ hs,
                                               const float* __restrict__ W,
                                               const float* __restrict__ bias,
                                               float* __restrict__ emis) {
  __shared__ float sW[TT * HH];  // 84 KiB
  __shared__ float sB[TT];
  {
    const float4* Wv = (const float4*)W;
    float4* sWv = (float4*)sW;
    for (int i = threadIdx.x; i < TT * HH / 4; i += 1024) sWv[i] = Wv[i];
    if (threadIdx.x < TT) sB[threadIdx.x] = bias[threadIdx.x];
  }
  __syncthreads();
  const int lane = threadIdx.x & 63;
  const int wid = threadIdx.x >> 6;
  const int gw = blockIdx.x * 16 + wid;  // 0..4095, 8 rows each
  for (int g = 0; g < 4; ++g) {
    const int row0 = gw * 8 + g * 2;
    float acc[2][TT];
#pragma unroll
    for (int r = 0; r < 2; ++r)
#pragma unroll
      for (int t = 0; t < TT; ++t) acc[r][t] = 0.f;
    const float4* hp0 = (const float4*)(hs + (size_t)row0 * HH);
    const float4* hp1 = (const float4*)(hs + (size_t)(row0 + 1) * HH);
#pragma unroll
    for (int c = 0; c < 4; ++c) {
      float4 h0 = hp0[c * 64 + lane];
      float4 h1 = hp1[c * 64 + lane];
#pragma unroll
      for (int t = 0; t < TT; ++t) {
        float4 wv = ((const float4*)(sW + t * HH))[c * 64 + lane];
        acc[0][t] = fmaf(h0.x, wv.x, acc[0][t]);
        acc[0][t] = fmaf(h0.y, wv.y, acc[0][t]);
        acc[0][t] = fmaf(h0.z, wv.z, acc[0][t]);
        acc[0][t] = fmaf(h0.w, wv.w, acc[0][t]);
        acc[1][t] = fmaf(h1.x, wv.x, acc[1][t]);
        acc[1][t] = fmaf(h1.y, wv.y, acc[1][t]);
        acc[1][t] = fmaf(h1.z, wv.z, acc[1][t]);
        acc[1][t] = fmaf(h1.w, wv.w, acc[1][t]);
      }
    }
#pragma unroll
    for (int r = 0; r < 2; ++r)
#pragma unroll
      for (int t = 0; t < TT; ++t) acc[r][t] = wave_sum(acc[r][t]);
    if (lane == 0) {
      float* ep = emis + (size_t)row0 * TT;
#pragma unroll
      for (int t = 0; t < TT; ++t) ep[t] = acc[0][t] + sB[t];
    }
    if (lane == 1) {
      float* ep = emis + (size_t)(row0 + 1) * TT;
#pragma unroll
      for (int t = 0; t < TT; ++t) ep[t] = acc[1][t] + sB[t];
    }
  }
}

// ---------------- Kernel 2: CRF forward scan + Viterbi ----------------
// (unchanged from round 1 — known correct; to be attacked next round)
__global__ __launch_bounds__(64) void k_scan(const float* __restrict__ emis,
                                             const int* __restrict__ mask,
                                             const float* __restrict__ trans,
                                             const float* __restrict__ sv,
                                             const float* __restrict__ ev,
                                             float* __restrict__ logZ,
                                             float* __restrict__ pred) {
  const int lane = threadIdx.x;
  const int g = lane >> 5;
  const int j = lane & 31;
  const bool act = (j < TT);
  const int jj = act ? j : 0;
  const int src0 = g << 5;
  const int b = (blockIdx.x & 31) * 2 + g;
  const size_t eb = (size_t)b * SS * TT;

  if (blockIdx.x < 32) {
    float E[TT];
#pragma unroll
    for (int i = 0; i < TT; ++i) E[i] = expf(trans[i * TT + jj]);
    float v = act ? expf(sv[jj] + emis[eb + jj]) : 0.f;
    float C = 0.f;
    for (int t = 1; t < SS; ++t) {
      float e = emis[eb + (size_t)t * TT + jj];
      int mk = mask[b * SS + t];
      float q0 = 0.f, q1 = 0.f, q2 = 0.f;
#pragma unroll
      for (int i = 0; i < TT; i += 3) {
        q0 = fmaf(__shfl(v, src0 + i), E[i], q0);
        q1 = fmaf(__shfl(v, src0 + i + 1), E[i + 1], q1);
        q2 = fmaf(__shfl(v, src0 + i + 2), E[i + 2], q2);
      }
      float vn = (q0 + q1 + q2) * expf(e);
      v = (act && mk) ? vn : v;
      if ((t & 7) == 0) {
        float m = v;
#pragma unroll
        for (int d = 16; d >= 1; d >>= 1) m = fmaxf(m, __shfl_xor(m, d));
        int ex = (int)((__float_as_uint(m) >> 23) & 255u) - 127;
        v *= __uint_as_float((unsigned)(127 - ex) << 23);
        C += (float)ex * 0.6931471805599453f;
      }
    }
    float wv = act ? v * expf(ev[jj]) : 0.f;
#pragma unroll
    for (int d = 16; d >= 1; d >>= 1) wv += __shfl_xor(wv, d);
    if (j == 0) logZ[b] = C + logf(wv);
  } else {
    __shared__ unsigned char bp[2][SS][32];  // 32KB
    float Tc[TT];
#pragma unroll
    for (int i = 0; i < TT; ++i) Tc[i] = trans[i * TT + jj];
    float sc = act ? (sv[jj] + emis[eb + jj]) : -3.0e38f;
    for (int t = 1; t < SS; ++t) {
      float e = emis[eb + (size_t)t * TT + jj];
      int mk = mask[b * SS + t];
      float best = -3.0e38f;
      int bi = 0;
#pragma unroll
      for (int i = 0; i < TT; ++i) {
        float x = __shfl(sc, src0 + i) + Tc[i];
        bool cgt = (x > best);
        best = cgt ? x : best;
        bi = cgt ? i : bi;
      }
      float ns = best + e;
      sc = (act && mk) ? ns : sc;
      bp[g][t][j] = (unsigned char)(mk ? bi : j);
    }
    __syncthreads();
    float fsv = act ? (sc + ev[jj]) : -3.0e38f;
    int idx = j;
#pragma unroll
    for (int d = 16; d >= 1; d >>= 1) {
      float ov = __shfl_xor(fsv, d);
      int oi = __shfl_xor(idx, d);
      bool take = (ov > fsv) || (ov == fsv && oi < idx);
      fsv = take ? ov : fsv;
      idx = take ? oi : idx;
    }
    if (j == 0) {
      int tag = idx;
      pred[b * SS + SS - 1] = (float)(mask[b * SS + SS - 1] ? tag : 0);
      for (int t = SS - 1; t >= 1; --t) {
        tag = bp[g][t][tag];
        pred[b * SS + t - 1] = (float)(mask[b * SS + t - 1] ? tag : 0);
      }
    }
  }
}

// ---------------- Kernel 3: numerator + loss, one block per batch ----------------
__global__ __launch_bounds__(64) void k_loss(const float* __restrict__ emis,
                                             const int* __restrict__ mask,
                                             const int* __restrict__ labels,
                                             const float* __restrict__ trans,
                                             const float* __restrict__ sv,
                                             const float* __restrict__ ev,
                                             const float* __restrict__ logZ,
                                             float* __restrict__ outv) {
  const int b = blockIdx.x;
  const int lane = threadIdx.x;
  float p = 0.f;
  int cnt = 0;
  for (int t = lane; t < SS; t += 64) {
    cnt += mask[b * SS + t] ? 1 : 0;
    if (t >= 1) {
      const int lp = labels[b * SS + t - 1];
      const int lc = labels[b * SS + t];
      const float mk = (float)mask[b * SS + t];
      p += mk * (trans[lp * TT + lc] + emis[((size_t)b * SS + t) * TT + lc]);
    }
  }
  p = wave_sum(p);
#pragma unroll
  for (int d = 32; d >= 1; d >>= 1) cnt += __shfl_xor(cnt, d);
  if (lane == 0) {
    const int l0 = labels[b * SS];
    float numer = p + sv[l0] + emis[(size_t)b * SS * TT + l0];
    numer += ev[labels[b * SS + cnt - 1]];
    atomicAdd(outv, logZ[b] - numer);  // loss = sum_b (logZ - numerator)
  }
}

extern "C" void kernel_launch(void* const* d_in, const int* in_sizes, int n_in,
                              void* d_out, int out_size, void* d_ws, size_t ws_size,
                              hipStream_t stream) {
  const float* hs = (const float*)d_in[0];
  const int* msk = (const int*)d_in[1];
  const int* lab = (const int*)d_in[2];
  const float* W = (const float*)d_in[3];
  const float* bias = (const float*)d_in[4];
  const float* trans = (const float*)d_in[5];
  const float* sv = (const float*)d_in[6];
  const float* ev = (const float*)d_in[7];
  float* out = (float*)d_out;

  float* emis = (float*)d_ws;                 // 64*512*21 floats
  float* logZ = emis + (size_t)BB * SS * TT;  // 64 floats

  hipMemsetAsync(d_out, 0, 4, stream);  // zero the loss accumulator
  k_emis<<<256, 1024, 0, stream>>>(hs, W, bias, emis);
  k_scan<<<64, 64, 0, stream>>>(emis, msk, trans, sv, ev, logZ, out + 1);
  k_loss<<<64, 64, 0, stream>>>(emis, msk, lab, trans, sv, ev, logZ, out);
}

// Round 3
// 1025.311 us; speedup vs baseline: 1.2697x; 1.0041x over previous
//
#include <hip/hip_runtime.h>
#include <math.h>
#include <stdint.h>

#define BB 64
#define SS 512
#define HH 1024
#define TT 21

// DPP-based partial reduce within row of 16, then cross-row shuffles.
template <int CTRL>
__device__ __forceinline__ float dpp_add(float v) {
  int t = __builtin_amdgcn_update_dpp(0, __float_as_int(v), CTRL, 0xF, 0xF, true);
  return v + __int_as_float(t);
}
__device__ __forceinline__ float wave_sum(float v) {
  v = dpp_add<0x121>(v);  // row_ror:1
  v = dpp_add<0x122>(v);  // row_ror:2
  v = dpp_add<0x124>(v);  // row_ror:4
  v = dpp_add<0x128>(v);  // row_ror:8
  v += __shfl_xor(v, 16);
  v += __shfl_xor(v, 32);
  return v;
}

// ---------------- Kernel 1: emissions = hs @ W^T + bias ----------------
// 256 blocks x 1024 threads (16 waves/CU, 1 block/CU due to 84KB LDS).
// __launch_bounds__(1024, 4): 16 waves co-resident REQUIRES <=128 VGPRs;
// stating min-waves=4 sets the cap to 128 (default heuristic chose 64 ->
// massive scratch spills, 500MB WRITE_SIZE in rounds 1-2).
__global__ __launch_bounds__(1024, 4) void k_emis(const float* __restrict__ hs,
                                                  const float* __restrict__ W,
                                                  const float* __restrict__ bias,
                                                  float* __restrict__ emis) {
  __shared__ float sW[TT * HH];  // 84 KiB
  __shared__ float sB[TT];
  {
    const float4* Wv = (const float4*)W;
    float4* sWv = (float4*)sW;
    for (int i = threadIdx.x; i < TT * HH / 4; i += 1024) sWv[i] = Wv[i];
    if (threadIdx.x < TT) sB[threadIdx.x] = bias[threadIdx.x];
  }
  __syncthreads();
  const int lane = threadIdx.x & 63;
  const int wid = threadIdx.x >> 6;
  const int gw = blockIdx.x * 16 + wid;  // 0..4095 waves, 8 rows each
  for (int g = 0; g < 4; ++g) {
    const int row0 = gw * 8 + g * 2;
    float acc[2][TT];
#pragma unroll
    for (int r = 0; r < 2; ++r)
#pragma unroll
      for (int t = 0; t < TT; ++t) acc[r][t] = 0.f;
    const float4* hp0 = (const float4*)(hs + (size_t)row0 * HH);
    const float4* hp1 = (const float4*)(hs + (size_t)(row0 + 1) * HH);
#pragma unroll
    for (int c = 0; c < 4; ++c) {
      float4 h0 = hp0[c * 64 + lane];
      float4 h1 = hp1[c * 64 + lane];
#pragma unroll
      for (int t = 0; t < TT; ++t) {
        float4 wv = ((const float4*)(sW + t * HH))[c * 64 + lane];
        acc[0][t] = fmaf(h0.x, wv.x, acc[0][t]);
        acc[0][t] = fmaf(h0.y, wv.y, acc[0][t]);
        acc[0][t] = fmaf(h0.z, wv.z, acc[0][t]);
        acc[0][t] = fmaf(h0.w, wv.w, acc[0][t]);
        acc[1][t] = fmaf(h1.x, wv.x, acc[1][t]);
        acc[1][t] = fmaf(h1.y, wv.y, acc[1][t]);
        acc[1][t] = fmaf(h1.z, wv.z, acc[1][t]);
        acc[1][t] = fmaf(h1.w, wv.w, acc[1][t]);
      }
    }
#pragma unroll
    for (int r = 0; r < 2; ++r)
#pragma unroll
      for (int t = 0; t < TT; ++t) acc[r][t] = wave_sum(acc[r][t]);
    if (lane == 0) {
      float* ep = emis + (size_t)row0 * TT;
#pragma unroll
      for (int t = 0; t < TT; ++t) ep[t] = acc[0][t] + sB[t];
    }
    if (lane == 1) {
      float* ep = emis + (size_t)(row0 + 1) * TT;
#pragma unroll
      for (int t = 0; t < TT; ++t) ep[t] = acc[1][t] + sB[t];
    }
  }
}

// ---------------- Kernel 2: CRF forward scan + Viterbi ----------------
// Blocks 0..31: CRF logsumexp scan (exp domain, 2 batches/block).
// Blocks 32..63: Viterbi. NEW: e/mask prefetched one timestep ahead so the
// ~200cyc L2 latency hides behind the 21-bpermute compute of step t.
__global__ __launch_bounds__(64) void k_scan(const float* __restrict__ emis,
                                             const int* __restrict__ mask,
                                             const float* __restrict__ trans,
                                             const float* __restrict__ sv,
                                             const float* __restrict__ ev,
                                             float* __restrict__ logZ,
                                             float* __restrict__ pred) {
  const int lane = threadIdx.x;
  const int g = lane >> 5;
  const int j = lane & 31;
  const bool act = (j < TT);
  const int jj = act ? j : 0;
  const int src0 = g << 5;
  const int b = (blockIdx.x & 31) * 2 + g;
  const size_t eb = (size_t)b * SS * TT;

  if (blockIdx.x < 32) {
    float E[TT];
#pragma unroll
    for (int i = 0; i < TT; ++i) E[i] = expf(trans[i * TT + jj]);
    float v = act ? expf(sv[jj] + emis[eb + jj]) : 0.f;
    float C = 0.f;
    float e_nx = emis[eb + TT + jj];
    int mk_nx = mask[b * SS + 1];
    for (int t = 1; t < SS; ++t) {
      const float e = e_nx;
      const int mk = mk_nx;
      const int tn = (t + 1 < SS) ? (t + 1) : (SS - 1);
      e_nx = emis[eb + (size_t)tn * TT + jj];
      mk_nx = mask[b * SS + tn];
      float q0 = 0.f, q1 = 0.f, q2 = 0.f;
#pragma unroll
      for (int i = 0; i < TT; i += 3) {
        q0 = fmaf(__shfl(v, src0 + i), E[i], q0);
        q1 = fmaf(__shfl(v, src0 + i + 1), E[i + 1], q1);
        q2 = fmaf(__shfl(v, src0 + i + 2), E[i + 2], q2);
      }
      float vn = (q0 + q1 + q2) * expf(e);
      v = (act && mk) ? vn : v;
      if ((t & 7) == 0) {
        float m = v;
#pragma unroll
        for (int d = 16; d >= 1; d >>= 1) m = fmaxf(m, __shfl_xor(m, d));
        int ex = (int)((__float_as_uint(m) >> 23) & 255u) - 127;
        v *= __uint_as_float((unsigned)(127 - ex) << 23);
        C += (float)ex * 0.6931471805599453f;
      }
    }
    float wv = act ? v * expf(ev[jj]) : 0.f;
#pragma unroll
    for (int d = 16; d >= 1; d >>= 1) wv += __shfl_xor(wv, d);
    if (j == 0) logZ[b] = C + logf(wv);
  } else {
    __shared__ unsigned char bp[2][SS][32];  // 32KB
    float Tc[TT];
#pragma unroll
    for (int i = 0; i < TT; ++i) Tc[i] = trans[i * TT + jj];
    float sc = act ? (sv[jj] + emis[eb + jj]) : -3.0e38f;
    float e_nx = emis[eb + TT + jj];
    int mk_nx = mask[b * SS + 1];
    for (int t = 1; t < SS; ++t) {
      const float e = e_nx;
      const int mk = mk_nx;
      const int tn = (t + 1 < SS) ? (t + 1) : (SS - 1);
      e_nx = emis[eb + (size_t)tn * TT + jj];
      mk_nx = mask[b * SS + tn];
      float best = -3.0e38f;
      int bi = 0;
#pragma unroll
      for (int i = 0; i < TT; ++i) {
        float x = __shfl(sc, src0 + i) + Tc[i];
        bool cgt = (x > best);  // strict >: first index wins ties (matches argmax)
        best = cgt ? x : best;
        bi = cgt ? i : bi;
      }
      float ns = best + e;
      sc = (act && mk) ? ns : sc;
      bp[g][t][j] = (unsigned char)(mk ? bi : j);
    }
    __syncthreads();
    float fsv = act ? (sc + ev[jj]) : -3.0e38f;
    int idx = j;
#pragma unroll
    for (int d = 16; d >= 1; d >>= 1) {
      float ov = __shfl_xor(fsv, d);
      int oi = __shfl_xor(idx, d);
      bool take = (ov > fsv) || (ov == fsv && oi < idx);
      fsv = take ? ov : fsv;
      idx = take ? oi : idx;
    }
    if (j == 0) {
      int tag = idx;
      pred[b * SS + SS - 1] = (float)(mask[b * SS + SS - 1] ? tag : 0);
      for (int t = SS - 1; t >= 1; --t) {
        tag = bp[g][t][tag];
        pred[b * SS + t - 1] = (float)(mask[b * SS + t - 1] ? tag : 0);
      }
    }
  }
}

// ---------------- Kernel 3: numerator + loss, one block per batch ----------------
__global__ __launch_bounds__(64) void k_loss(const float* __restrict__ emis,
                                             const int* __restrict__ mask,
                                             const int* __restrict__ labels,
                                             const float* __restrict__ trans,
                                             const float* __restrict__ sv,
                                             const float* __restrict__ ev,
                                             const float* __restrict__ logZ,
                                             float* __restrict__ outv) {
  const int b = blockIdx.x;
  const int lane = threadIdx.x;
  float p = 0.f;
  int cnt = 0;
  for (int t = lane; t < SS; t += 64) {
    cnt += mask[b * SS + t] ? 1 : 0;
    if (t >= 1) {
      const int lp = labels[b * SS + t - 1];
      const int lc = labels[b * SS + t];
      const float mk = (float)mask[b * SS + t];
      p += mk * (trans[lp * TT + lc] + emis[((size_t)b * SS + t) * TT + lc]);
    }
  }
  p = wave_sum(p);
#pragma unroll
  for (int d = 32; d >= 1; d >>= 1) cnt += __shfl_xor(cnt, d);
  if (lane == 0) {
    const int l0 = labels[b * SS];
    float numer = p + sv[l0] + emis[(size_t)b * SS * TT + l0];
    numer += ev[labels[b * SS + cnt - 1]];
    atomicAdd(outv, logZ[b] - numer);  // loss = sum_b (logZ - numerator)
  }
}

extern "C" void kernel_launch(void* const* d_in, const int* in_sizes, int n_in,
                              void* d_out, int out_size, void* d_ws, size_t ws_size,
                              hipStream_t stream) {
  const float* hs = (const float*)d_in[0];
  const int* msk = (const int*)d_in[1];
  const int* lab = (const int*)d_in[2];
  const float* W = (const float*)d_in[3];
  const float* bias = (const float*)d_in[4];
  const float* trans = (const float*)d_in[5];
  const float* sv = (const float*)d_in[6];
  const float* ev = (const float*)d_in[7];
  float* out = (float*)d_out;

  float* emis = (float*)d_ws;                 // 64*512*21 floats
  float* logZ = emis + (size_t)BB * SS * TT;  // 64 floats

  hipMemsetAsync(d_out, 0, 4, stream);  // zero the loss accumulator
  k_emis<<<256, 1024, 0, stream>>>(hs, W, bias, emis);
  k_scan<<<64, 64, 0, stream>>>(emis, msk, trans, sv, ev, logZ, out + 1);
  k_loss<<<64, 64, 0, stream>>>(emis, msk, lab, trans, sv, ev, logZ, out);
}

// Round 4
// 930.742 us; speedup vs baseline: 1.3988x; 1.1016x over previous
//
#include <hip/hip_runtime.h>
#include <math.h>
#include <stdint.h>

#define BB 64
#define SS 512
#define HH 1024
#define TT 21

// DPP-based partial reduce within row of 16, then cross-row shuffles.
template <int CTRL>
__device__ __forceinline__ float dpp_add(float v) {
  int t = __builtin_amdgcn_update_dpp(0, __float_as_int(v), CTRL, 0xF, 0xF, true);
  return v + __int_as_float(t);
}
__device__ __forceinline__ float wave_sum(float v) {
  v = dpp_add<0x121>(v);  // row_ror:1
  v = dpp_add<0x122>(v);  // row_ror:2
  v = dpp_add<0x124>(v);  // row_ror:4
  v = dpp_add<0x128>(v);  // row_ror:8
  v += __shfl_xor(v, 16);
  v += __shfl_xor(v, 32);
  return v;
}

// ---------------- Kernel 1: emissions = hs @ W^T + bias ----------------
// 512 blocks x 512 threads. W (84KB) in LDS. Round-1 evidence: this exact
// launch config grants 128 VGPRs; 1024-thread blocks are hard-capped at 64
// by the toolchain (rounds 2-3: 500MB scratch WRITE_SIZE). Live set here:
// acc[2][21]=42 + h 8 + wv/addr ~ 80 < 128 -> no spill expected.
__global__ __launch_bounds__(512, 2) void k_emis(const float* __restrict__ hs,
                                                 const float* __restrict__ W,
                                                 const float* __restrict__ bias,
                                                 float* __restrict__ emis) {
  __shared__ float sW[TT * HH];  // 84 KiB
  __shared__ float sB[TT];
  {
    const float4* Wv = (const float4*)W;
    float4* sWv = (float4*)sW;
    for (int i = threadIdx.x; i < TT * HH / 4; i += 512) sWv[i] = Wv[i];
    if (threadIdx.x < TT) sB[threadIdx.x] = bias[threadIdx.x];
  }
  __syncthreads();
  const int lane = threadIdx.x & 63;
  const int wid = threadIdx.x >> 6;        // 0..7
  const int gw = blockIdx.x * 8 + wid;     // 0..4095 waves, 8 rows each
  for (int g = 0; g < 4; ++g) {
    const int row0 = gw * 8 + g * 2;
    float acc[2][TT];
#pragma unroll
    for (int r = 0; r < 2; ++r)
#pragma unroll
      for (int t = 0; t < TT; ++t) acc[r][t] = 0.f;
    const float4* hp0 = (const float4*)(hs + (size_t)row0 * HH);
    const float4* hp1 = (const float4*)(hs + (size_t)(row0 + 1) * HH);
#pragma unroll
    for (int c = 0; c < 4; ++c) {
      float4 h0 = hp0[c * 64 + lane];
      float4 h1 = hp1[c * 64 + lane];
#pragma unroll
      for (int t = 0; t < TT; ++t) {
        float4 wv = ((const float4*)(sW + t * HH))[c * 64 + lane];
        acc[0][t] = fmaf(h0.x, wv.x, acc[0][t]);
        acc[0][t] = fmaf(h0.y, wv.y, acc[0][t]);
        acc[0][t] = fmaf(h0.z, wv.z, acc[0][t]);
        acc[0][t] = fmaf(h0.w, wv.w, acc[0][t]);
        acc[1][t] = fmaf(h1.x, wv.x, acc[1][t]);
        acc[1][t] = fmaf(h1.y, wv.y, acc[1][t]);
        acc[1][t] = fmaf(h1.z, wv.z, acc[1][t]);
        acc[1][t] = fmaf(h1.w, wv.w, acc[1][t]);
      }
    }
#pragma unroll
    for (int r = 0; r < 2; ++r)
#pragma unroll
      for (int t = 0; t < TT; ++t) acc[r][t] = wave_sum(acc[r][t]);
    if (lane == 0) {
      float* ep = emis + (size_t)row0 * TT;
#pragma unroll
      for (int t = 0; t < TT; ++t) ep[t] = acc[0][t] + sB[t];
    }
    if (lane == 1) {
      float* ep = emis + (size_t)(row0 + 1) * TT;
#pragma unroll
      for (int t = 0; t < TT; ++t) ep[t] = acc[1][t] + sB[t];
    }
  }
}

// ---------------- Kernel 2: CRF forward scan + Viterbi ----------------
// __launch_bounds__(64, 1): single-wave blocks need the FULL VGPR budget —
// E[21]/Tc[21] + 21 hoisted bpermute-address regs + state exceeds the
// compiler's default high-occupancy cap and would spill inside a 511-deep
// serial loop (suspected cause of the ~360us residual in rounds 2-3).
__global__ __launch_bounds__(64, 1) void k_scan(const float* __restrict__ emis,
                                                const int* __restrict__ mask,
                                                const float* __restrict__ trans,
                                                const float* __restrict__ sv,
                                                const float* __restrict__ ev,
                                                float* __restrict__ logZ,
                                                float* __restrict__ pred) {
  const int lane = threadIdx.x;
  const int g = lane >> 5;
  const int j = lane & 31;
  const bool act = (j < TT);
  const int jj = act ? j : 0;
  const int src0 = g << 5;
  const int b = (blockIdx.x & 31) * 2 + g;
  const size_t eb = (size_t)b * SS * TT;

  if (blockIdx.x < 32) {
    // ---- CRF logsumexp scan in exp domain ----
    float E[TT];
#pragma unroll
    for (int i = 0; i < TT; ++i) E[i] = expf(trans[i * TT + jj]);
    float v = act ? expf(sv[jj] + emis[eb + jj]) : 0.f;
    float C = 0.f;
    float e_nx = emis[eb + TT + jj];
    int mk_nx = mask[b * SS + 1];
    for (int t = 1; t < SS; ++t) {
      const float e = e_nx;
      const int mk = mk_nx;
      const int tn = (t + 1 < SS) ? (t + 1) : (SS - 1);
      e_nx = emis[eb + (size_t)tn * TT + jj];
      mk_nx = mask[b * SS + tn];
      float q0 = 0.f, q1 = 0.f, q2 = 0.f;
#pragma unroll
      for (int i = 0; i < TT; i += 3) {
        q0 = fmaf(__shfl(v, src0 + i), E[i], q0);
        q1 = fmaf(__shfl(v, src0 + i + 1), E[i + 1], q1);
        q2 = fmaf(__shfl(v, src0 + i + 2), E[i + 2], q2);
      }
      float vn = (q0 + q1 + q2) * expf(e);
      v = (act && mk) ? vn : v;
      if ((t & 7) == 0) {
        float m = v;
#pragma unroll
        for (int d = 16; d >= 1; d >>= 1) m = fmaxf(m, __shfl_xor(m, d));
        int ex = (int)((__float_as_uint(m) >> 23) & 255u) - 127;
        v *= __uint_as_float((unsigned)(127 - ex) << 23);
        C += (float)ex * 0.6931471805599453f;
      }
    }
    float wv = act ? v * expf(ev[jj]) : 0.f;
#pragma unroll
    for (int d = 16; d >= 1; d >>= 1) wv += __shfl_xor(wv, d);
    if (j == 0) logZ[b] = C + logf(wv);
  } else {
    // ---- Viterbi: 3 parallel argmax chains (depth 7) + tie-safe merge ----
    __shared__ unsigned char bp[2][SS][32];  // 32KB
    float Tc[TT];
#pragma unroll
    for (int i = 0; i < TT; ++i) Tc[i] = trans[i * TT + jj];
    float sc = act ? (sv[jj] + emis[eb + jj]) : -3.0e38f;
    float e_nx = emis[eb + TT + jj];
    int mk_nx = mask[b * SS + 1];
    for (int t = 1; t < SS; ++t) {
      const float e = e_nx;
      const int mk = mk_nx;
      const int tn = (t + 1 < SS) ? (t + 1) : (SS - 1);
      e_nx = emis[eb + (size_t)tn * TT + jj];
      mk_nx = mask[b * SS + tn];
      float b0 = -3.0e38f, b1 = -3.0e38f, b2 = -3.0e38f;
      int i0 = 0, i1 = 0, i2 = 0;
#pragma unroll
      for (int i = 0; i < TT; i += 3) {
        float x0 = __shfl(sc, src0 + i) + Tc[i];
        float x1 = __shfl(sc, src0 + i + 1) + Tc[i + 1];
        float x2 = __shfl(sc, src0 + i + 2) + Tc[i + 2];
        if (x0 > b0) { b0 = x0; i0 = i; }
        if (x1 > b1) { b1 = x1; i1 = i + 1; }
        if (x2 > b2) { b2 = x2; i2 = i + 2; }
      }
      // merge with first-index tie-break (matches jnp.argmax)
      float best = b0;
      int bi = i0;
      if (b1 > best || (b1 == best && i1 < bi)) { best = b1; bi = i1; }
      if (b2 > best || (b2 == best && i2 < bi)) { best = b2; bi = i2; }
      float ns = best + e;
      sc = (act && mk) ? ns : sc;
      bp[g][t][j] = (unsigned char)(mk ? bi : j);
    }
    __syncthreads();
    float fsv = act ? (sc + ev[jj]) : -3.0e38f;
    int idx = j;
#pragma unroll
    for (int d = 16; d >= 1; d >>= 1) {
      float ov = __shfl_xor(fsv, d);
      int oi = __shfl_xor(idx, d);
      bool take = (ov > fsv) || (ov == fsv && oi < idx);
      fsv = take ? ov : fsv;
      idx = take ? oi : idx;
    }
    if (j == 0) {
      int tag = idx;
      pred[b * SS + SS - 1] = (float)(mask[b * SS + SS - 1] ? tag : 0);
      for (int t = SS - 1; t >= 1; --t) {
        tag = bp[g][t][tag];
        pred[b * SS + t - 1] = (float)(mask[b * SS + t - 1] ? tag : 0);
      }
    }
  }
}

// ---------------- Kernel 3: numerator + loss, one block per batch ----------------
__global__ __launch_bounds__(64, 1) void k_loss(const float* __restrict__ emis,
                                                const int* __restrict__ mask,
                                                const int* __restrict__ labels,
                                                const float* __restrict__ trans,
                                                const float* __restrict__ sv,
                                                const float* __restrict__ ev,
                                                const float* __restrict__ logZ,
                                                float* __restrict__ outv) {
  const int b = blockIdx.x;
  const int lane = threadIdx.x;
  float p = 0.f;
  int cnt = 0;
  for (int t = lane; t < SS; t += 64) {
    cnt += mask[b * SS + t] ? 1 : 0;
    if (t >= 1) {
      const int lp = labels[b * SS + t - 1];
      const int lc = labels[b * SS + t];
      const float mk = (float)mask[b * SS + t];
      p += mk * (trans[lp * TT + lc] + emis[((size_t)b * SS + t) * TT + lc]);
    }
  }
  p = wave_sum(p);
#pragma unroll
  for (int d = 32; d >= 1; d >>= 1) cnt += __shfl_xor(cnt, d);
  if (lane == 0) {
    const int l0 = labels[b * SS];
    float numer = p + sv[l0] + emis[(size_t)b * SS * TT + l0];
    numer += ev[labels[b * SS + cnt - 1]];
    atomicAdd(outv, logZ[b] - numer);  // loss = sum_b (logZ - numerator)
  }
}

extern "C" void kernel_launch(void* const* d_in, const int* in_sizes, int n_in,
                              void* d_out, int out_size, void* d_ws, size_t ws_size,
                              hipStream_t stream) {
  const float* hs = (const float*)d_in[0];
  const int* msk = (const int*)d_in[1];
  const int* lab = (const int*)d_in[2];
  const float* W = (const float*)d_in[3];
  const float* bias = (const float*)d_in[4];
  const float* trans = (const float*)d_in[5];
  const float* sv = (const float*)d_in[6];
  const float* ev = (const float*)d_in[7];
  float* out = (float*)d_out;

  float* emis = (float*)d_ws;                 // 64*512*21 floats
  float* logZ = emis + (size_t)BB * SS * TT;  // 64 floats

  hipMemsetAsync(d_out, 0, 4, stream);  // zero the loss accumulator
  k_emis<<<512, 512, 0, stream>>>(hs, W, bias, emis);
  k_scan<<<64, 64, 0, stream>>>(emis, msk, trans, sv, ev, logZ, out + 1);
  k_loss<<<64, 64, 0, stream>>>(emis, msk, lab, trans, sv, ev, logZ, out);
}

// Round 5
// 709.970 us; speedup vs baseline: 1.8337x; 1.3110x over previous
//
#include <hip/hip_runtime.h>
#include <math.h>
#include <stdint.h>

#define BB 64
#define SS 512
#define HH 1024
#define TT 21

// DPP-based partial reduce within row of 16, then cross-row shuffles.
template <int CTRL>
__device__ __forceinline__ float dpp_add(float v) {
  int t = __builtin_amdgcn_update_dpp(0, __float_as_int(v), CTRL, 0xF, 0xF, true);
  return v + __int_as_float(t);
}
__device__ __forceinline__ float wave_sum(float v) {
  v = dpp_add<0x121>(v);  // row_ror:1
  v = dpp_add<0x122>(v);  // row_ror:2
  v = dpp_add<0x124>(v);  // row_ror:4
  v = dpp_add<0x128>(v);  // row_ror:8
  v += __shfl_xor(v, 16);
  v += __shfl_xor(v, 32);
  return v;
}

// ---------------- Kernel 1: emissions = hs @ W^T + bias ----------------
// 512 blocks x 512 threads, W (84KB) in LDS, 128-VGPR config (round-1/4
// evidence). Round-4 lesson: the fully-unrolled t-loop hoisted 21 float4
// LDS loads (84 regs) -> spill (477MB scratch writes). '#pragma unroll 3'
// caps live wv at ~12 regs; live set ~70 < 128 -> no spill.
__global__ __launch_bounds__(512, 2) void k_emis(const float* __restrict__ hs,
                                                 const float* __restrict__ W,
                                                 const float* __restrict__ bias,
                                                 float* __restrict__ emis) {
  __shared__ float sW[TT * HH];  // 84 KiB
  __shared__ float sB[TT];
  {
    const float4* Wv = (const float4*)W;
    float4* sWv = (float4*)sW;
    for (int i = threadIdx.x; i < TT * HH / 4; i += 512) sWv[i] = Wv[i];
    if (threadIdx.x < TT) sB[threadIdx.x] = bias[threadIdx.x];
  }
  __syncthreads();
  const int lane = threadIdx.x & 63;
  const int wid = threadIdx.x >> 6;     // 0..7
  const int gw = blockIdx.x * 8 + wid;  // 0..4095 waves, 8 rows each
  for (int g = 0; g < 4; ++g) {
    const int row0 = gw * 8 + g * 2;
    float acc[2][TT];
#pragma unroll
    for (int r = 0; r < 2; ++r)
#pragma unroll
      for (int t = 0; t < TT; ++t) acc[r][t] = 0.f;
    const float4* hp0 = (const float4*)(hs + (size_t)row0 * HH);
    const float4* hp1 = (const float4*)(hs + (size_t)(row0 + 1) * HH);
#pragma unroll
    for (int c = 0; c < 4; ++c) {
      float4 h0 = hp0[c * 64 + lane];
      float4 h1 = hp1[c * 64 + lane];
#pragma unroll 3
      for (int t = 0; t < TT; ++t) {
        float4 wv = ((const float4*)(sW + t * HH))[c * 64 + lane];
        acc[0][t] = fmaf(h0.x, wv.x, acc[0][t]);
        acc[0][t] = fmaf(h0.y, wv.y, acc[0][t]);
        acc[0][t] = fmaf(h0.z, wv.z, acc[0][t]);
        acc[0][t] = fmaf(h0.w, wv.w, acc[0][t]);
        acc[1][t] = fmaf(h1.x, wv.x, acc[1][t]);
        acc[1][t] = fmaf(h1.y, wv.y, acc[1][t]);
        acc[1][t] = fmaf(h1.z, wv.z, acc[1][t]);
        acc[1][t] = fmaf(h1.w, wv.w, acc[1][t]);
      }
    }
#pragma unroll
    for (int r = 0; r < 2; ++r)
#pragma unroll
      for (int t = 0; t < TT; ++t) acc[r][t] = wave_sum(acc[r][t]);
    if (lane == 0) {
      float* ep = emis + (size_t)row0 * TT;
#pragma unroll
      for (int t = 0; t < TT; ++t) ep[t] = acc[0][t] + sB[t];
    }
    if (lane == 1) {
      float* ep = emis + (size_t)(row0 + 1) * TT;
#pragma unroll
      for (int t = 0; t < TT; ++t) ep[t] = acc[1][t] + sB[t];
    }
  }
}

// ---------------- Kernel 2: CRF forward scan + Viterbi ----------------
// Blocks 0..31: CRF logsumexp scan in exp domain. Round-4 lesson: libm
// expf is a branchy libcall sitting ON the critical path; use native
// __expf and compute it one iteration ahead (it only depends on the
// prefetched emission, not on the recurrence).
__global__ __launch_bounds__(64, 1) void k_scan(const float* __restrict__ emis,
                                                const int* __restrict__ mask,
                                                const float* __restrict__ trans,
                                                const float* __restrict__ sv,
                                                const float* __restrict__ ev,
                                                float* __restrict__ logZ,
                                                float* __restrict__ pred) {
  const int lane = threadIdx.x;
  const int g = lane >> 5;
  const int j = lane & 31;
  const bool act = (j < TT);
  const int jj = act ? j : 0;
  const int src0 = g << 5;
  const int b = (blockIdx.x & 31) * 2 + g;
  const size_t eb = (size_t)b * SS * TT;

  if (blockIdx.x < 32) {
    // ---- CRF logsumexp scan (exp domain, v = exp(alpha - C)) ----
    float E[TT];
#pragma unroll
    for (int i = 0; i < TT; ++i) E[i] = __expf(trans[i * TT + jj]);
    float v = act ? __expf(sv[jj] + emis[eb + jj]) : 0.f;
    float C = 0.f;
    float e_nx = emis[eb + TT + jj];
    int mk_nx = mask[b * SS + 1];
    float g_nx = __expf(e_nx);  // exp of emission for t=1, ready before loop
    for (int t = 1; t < SS; ++t) {
      const float ge = g_nx;  // = exp(emis[t]) — computed last iteration
      const int mk = mk_nx;
      const int tn = (t + 1 < SS) ? (t + 1) : (SS - 1);
      e_nx = emis[eb + (size_t)tn * TT + jj];
      mk_nx = mask[b * SS + tn];
      g_nx = __expf(e_nx);  // off the critical path: consumed next iter
      float q0 = 0.f, q1 = 0.f, q2 = 0.f;
#pragma unroll
      for (int i = 0; i < TT; i += 3) {
        q0 = fmaf(__shfl(v, src0 + i), E[i], q0);
        q1 = fmaf(__shfl(v, src0 + i + 1), E[i + 1], q1);
        q2 = fmaf(__shfl(v, src0 + i + 2), E[i + 2], q2);
      }
      float vn = (q0 + q1 + q2) * ge;
      v = (act && mk) ? vn : v;
      if ((t & 7) == 0) {
        // renorm by power of 2 of group max (exact; C compensates)
        float m = v;
#pragma unroll
        for (int d = 16; d >= 1; d >>= 1) m = fmaxf(m, __shfl_xor(m, d));
        int ex = (int)((__float_as_uint(m) >> 23) & 255u) - 127;
        v *= __uint_as_float((unsigned)(127 - ex) << 23);
        C += (float)ex * 0.6931471805599453f;
      }
    }
    float wv = act ? v * __expf(ev[jj]) : 0.f;
#pragma unroll
    for (int d = 16; d >= 1; d >>= 1) wv += __shfl_xor(wv, d);
    if (j == 0) logZ[b] = C + __logf(wv);
  } else {
    // ---- Viterbi: 3 parallel argmax chains + tie-safe merge ----
    __shared__ unsigned char bp[2][SS][32];  // 32KB
    float Tc[TT];
#pragma unroll
    for (int i = 0; i < TT; ++i) Tc[i] = trans[i * TT + jj];
    float sc = act ? (sv[jj] + emis[eb + jj]) : -3.0e38f;
    float e_nx = emis[eb + TT + jj];
    int mk_nx = mask[b * SS + 1];
    for (int t = 1; t < SS; ++t) {
      const float e = e_nx;
      const int mk = mk_nx;
      const int tn = (t + 1 < SS) ? (t + 1) : (SS - 1);
      e_nx = emis[eb + (size_t)tn * TT + jj];
      mk_nx = mask[b * SS + tn];
      float b0 = -3.0e38f, b1 = -3.0e38f, b2 = -3.0e38f;
      int i0 = 0, i1 = 0, i2 = 0;
#pragma unroll
      for (int i = 0; i < TT; i += 3) {
        float x0 = __shfl(sc, src0 + i) + Tc[i];
        float x1 = __shfl(sc, src0 + i + 1) + Tc[i + 1];
        float x2 = __shfl(sc, src0 + i + 2) + Tc[i + 2];
        if (x0 > b0) { b0 = x0; i0 = i; }
        if (x1 > b1) { b1 = x1; i1 = i + 1; }
        if (x2 > b2) { b2 = x2; i2 = i + 2; }
      }
      // merge with first-index tie-break (matches jnp.argmax)
      float best = b0;
      int bi = i0;
      if (b1 > best || (b1 == best && i1 < bi)) { best = b1; bi = i1; }
      if (b2 > best || (b2 == best && i2 < bi)) { best = b2; bi = i2; }
      float ns = best + e;
      sc = (act && mk) ? ns : sc;
      bp[g][t][j] = (unsigned char)(mk ? bi : j);
    }
    __syncthreads();
    float fsv = act ? (sc + ev[jj]) : -3.0e38f;
    int idx = j;
#pragma unroll
    for (int d = 16; d >= 1; d >>= 1) {
      float ov = __shfl_xor(fsv, d);
      int oi = __shfl_xor(idx, d);
      bool take = (ov > fsv) || (ov == fsv && oi < idx);
      fsv = take ? ov : fsv;
      idx = take ? oi : idx;
    }
    if (j == 0) {
      int tag = idx;
      pred[b * SS + SS - 1] = (float)(mask[b * SS + SS - 1] ? tag : 0);
      for (int t = SS - 1; t >= 1; --t) {
        tag = bp[g][t][tag];
        pred[b * SS + t - 1] = (float)(mask[b * SS + t - 1] ? tag : 0);
      }
    }
  }
}

// ---------------- Kernel 3: numerator + loss, one block per batch ----------------
__global__ __launch_bounds__(64, 1) void k_loss(const float* __restrict__ emis,
                                                const int* __restrict__ mask,
                                                const int* __restrict__ labels,
                                                const float* __restrict__ trans,
                                                const float* __restrict__ sv,
                                                const float* __restrict__ ev,
                                                const float* __restrict__ logZ,
                                                float* __restrict__ outv) {
  const int b = blockIdx.x;
  const int lane = threadIdx.x;
  float p = 0.f;
  int cnt = 0;
  for (int t = lane; t < SS; t += 64) {
    cnt += mask[b * SS + t] ? 1 : 0;
    if (t >= 1) {
      const int lp = labels[b * SS + t - 1];
      const int lc = labels[b * SS + t];
      const float mk = (float)mask[b * SS + t];
      p += mk * (trans[lp * TT + lc] + emis[((size_t)b * SS + t) * TT + lc]);
    }
  }
  p = wave_sum(p);
#pragma unroll
  for (int d = 32; d >= 1; d >>= 1) cnt += __shfl_xor(cnt, d);
  if (lane == 0) {
    const int l0 = labels[b * SS];
    float numer = p + sv[l0] + emis[(size_t)b * SS * TT + l0];
    numer += ev[labels[b * SS + cnt - 1]];
    atomicAdd(outv, logZ[b] - numer);  // loss = sum_b (logZ - numerator)
  }
}

extern "C" void kernel_launch(void* const* d_in, const int* in_sizes, int n_in,
                              void* d_out, int out_size, void* d_ws, size_t ws_size,
                              hipStream_t stream) {
  const float* hs = (const float*)d_in[0];
  const int* msk = (const int*)d_in[1];
  const int* lab = (const int*)d_in[2];
  const float* W = (const float*)d_in[3];
  const float* bias = (const float*)d_in[4];
  const float* trans = (const float*)d_in[5];
  const float* sv = (const float*)d_in[6];
  const float* ev = (const float*)d_in[7];
  float* out = (float*)d_out;

  float* emis = (float*)d_ws;                 // 64*512*21 floats
  float* logZ = emis + (size_t)BB * SS * TT;  // 64 floats

  hipMemsetAsync(d_out, 0, 4, stream);  // zero the loss accumulator
  k_emis<<<512, 512, 0, stream>>>(hs, W, bias, emis);
  k_scan<<<64, 64, 0, stream>>>(emis, msk, trans, sv, ev, logZ, out + 1);
  k_loss<<<64, 64, 0, stream>>>(emis, msk, lab, trans, sv, ev, logZ, out);
}

// Round 6
// 473.958 us; speedup vs baseline: 2.7468x; 1.4980x over previous
//
#include <hip/hip_runtime.h>
#include <math.h>
#include <stdint.h>

#define BB 64
#define SS 512
#define HH 1024
#define TT 21

// DPP-based partial reduce within row of 16, then cross-row shuffles.
template <int CTRL>
__device__ __forceinline__ float dpp_add(float v) {
  int t = __builtin_amdgcn_update_dpp(0, __float_as_int(v), CTRL, 0xF, 0xF, true);
  return v + __int_as_float(t);
}
__device__ __forceinline__ float wave_sum(float v) {
  v = dpp_add<0x121>(v);  // row_ror:1
  v = dpp_add<0x122>(v);  // row_ror:2
  v = dpp_add<0x124>(v);  // row_ror:4
  v = dpp_add<0x128>(v);  // row_ror:8
  v += __shfl_xor(v, 16);
  v += __shfl_xor(v, 32);
  return v;
}

#define DOT4(A, H, WV)        \
  A = fmaf(H.x, WV.x, A);     \
  A = fmaf(H.y, WV.y, A);     \
  A = fmaf(H.z, WV.z, A);     \
  A = fmaf(H.w, WV.w, A)

// ---------------- Kernel 1: emissions = hs @ W^T + bias ----------------
// 512 blocks x 512 threads, W (84KB) in LDS.
// Round-4 lesson: fully-unrolled t-loop hoists 21 float4 LDS loads -> VGPR
// spill. Round-5 lesson: partial unroll makes acc[] runtime-indexed ->
// scratch array (743MB writes!). Fix: SCALAR accumulators, outer t-group
// loop NOT unrolled (7 iters x 3 tags), wv registers reused per c.
// Live set ~ h(32) + wv(12) + acc(6) + addr ~ 60 VGPRs.
__global__ __launch_bounds__(512, 2) void k_emis(const float* __restrict__ hs,
                                                 const float* __restrict__ W,
                                                 const float* __restrict__ bias,
                                                 float* __restrict__ emis) {
  __shared__ float sW[TT * HH];  // 84 KiB
  __shared__ float sB[TT];
  {
    const float4* Wv = (const float4*)W;
    float4* sWv = (float4*)sW;
    for (int i = threadIdx.x; i < TT * HH / 4; i += 512) sWv[i] = Wv[i];
    if (threadIdx.x < TT) sB[threadIdx.x] = bias[threadIdx.x];
  }
  __syncthreads();
  const int lane = threadIdx.x & 63;
  const int wid = threadIdx.x >> 6;     // 0..7
  const int gw = blockIdx.x * 8 + wid;  // 0..4095 waves, 8 rows each
  for (int g = 0; g < 4; ++g) {
    const int row0 = gw * 8 + g * 2;
    const float4* hp0 = (const float4*)(hs + (size_t)row0 * HH);
    const float4* hp1 = (const float4*)(hs + (size_t)(row0 + 1) * HH);
    float4 h0[4], h1[4];
#pragma unroll
    for (int c = 0; c < 4; ++c) {
      h0[c] = hp0[c * 64 + lane];
      h1[c] = hp1[c * 64 + lane];
    }
    float* ep0 = emis + (size_t)row0 * TT;
    float* ep1 = ep0 + TT;
#pragma unroll 1
    for (int tg = 0; tg < TT; tg += 3) {
      float a00 = 0.f, a01 = 0.f, a02 = 0.f;
      float a10 = 0.f, a11 = 0.f, a12 = 0.f;
#pragma unroll
      for (int c = 0; c < 4; ++c) {
        float4 w0 = ((const float4*)(sW + (tg + 0) * HH))[c * 64 + lane];
        float4 w1 = ((const float4*)(sW + (tg + 1) * HH))[c * 64 + lane];
        float4 w2 = ((const float4*)(sW + (tg + 2) * HH))[c * 64 + lane];
        DOT4(a00, h0[c], w0);
        DOT4(a01, h0[c], w1);
        DOT4(a02, h0[c], w2);
        DOT4(a10, h1[c], w0);
        DOT4(a11, h1[c], w1);
        DOT4(a12, h1[c], w2);
      }
      a00 = wave_sum(a00);
      a01 = wave_sum(a01);
      a02 = wave_sum(a02);
      a10 = wave_sum(a10);
      a11 = wave_sum(a11);
      a12 = wave_sum(a12);
      if (lane == 0) {
        ep0[tg] = a00 + sB[tg];
        ep0[tg + 1] = a01 + sB[tg + 1];
        ep0[tg + 2] = a02 + sB[tg + 2];
      }
      if (lane == 1) {
        ep1[tg] = a10 + sB[tg];
        ep1[tg + 1] = a11 + sB[tg + 1];
        ep1[tg + 2] = a12 + sB[tg + 2];
      }
    }
  }
}

// ---------------- Kernel 2: CRF forward scan + Viterbi ----------------
// Round-5 lesson: the ~370us was the per-iteration emis load — emis is
// written by k_emis on OTHER XCDs, so k_scan's reads miss local L2
// (~400-900cyc) and a 1-deep prefetch can't hide it. Fix: stage the whole
// per-block emission slice (2 batches x 512 x 21 = 84KB) + mask into LDS
// with coalesced float4 loads, then the serial scan reads LDS only.
__global__ __launch_bounds__(64, 1) void k_scan(const float* __restrict__ emis,
                                                const int* __restrict__ mask,
                                                const float* __restrict__ trans,
                                                const float* __restrict__ sv,
                                                const float* __restrict__ ev,
                                                float* __restrict__ logZ,
                                                float* __restrict__ pred) {
  __shared__ float sE[2 * SS * TT];        // 84 KiB
  __shared__ int sM[2 * SS];               // 4 KiB
  __shared__ unsigned char bp[2][SS][32];  // 32 KiB (viterbi only)
  __shared__ unsigned char sTag[2][SS];    // 1 KiB  (viterbi only)
  const int lane = threadIdx.x;
  const int g = lane >> 5;
  const int j = lane & 31;
  const bool act = (j < TT);
  const int jj = act ? j : 0;
  const int src0 = g << 5;
  const int b0 = (blockIdx.x & 31) * 2;
  const int b = b0 + g;

  // ---- stage emissions + mask for both batches of this block ----
  {
    const float4* src = (const float4*)(emis + (size_t)b0 * SS * TT);
    float4* dst = (float4*)sE;
    for (int i = lane; i < 2 * SS * TT / 4; i += 64) dst[i] = src[i];
    const int* msrc = mask + b0 * SS;
    for (int i = lane; i < 2 * SS; i += 64) sM[i] = msrc[i];
  }
  __syncthreads();
  const float* myE = sE + g * SS * TT;
  const int* myM = sM + g * SS;

  if (blockIdx.x < 32) {
    // ---- CRF logsumexp scan (exp domain, v = exp(alpha - C)) ----
    float E[TT];
#pragma unroll
    for (int i = 0; i < TT; ++i) E[i] = __expf(trans[i * TT + jj]);
    float v = act ? __expf(sv[jj] + myE[jj]) : 0.f;
    float C = 0.f;
    float ge_nx = __expf(myE[TT + jj]);
    int mk_nx = myM[1];
    for (int t = 1; t < SS; ++t) {
      const float ge = ge_nx;
      const int mk = mk_nx;
      const int tn = (t + 1 < SS) ? (t + 1) : (SS - 1);
      ge_nx = __expf(myE[tn * TT + jj]);  // LDS read + exp, consumed next iter
      mk_nx = myM[tn];
      float q0 = 0.f, q1 = 0.f, q2 = 0.f;
#pragma unroll
      for (int i = 0; i < TT; i += 3) {
        q0 = fmaf(__shfl(v, src0 + i), E[i], q0);
        q1 = fmaf(__shfl(v, src0 + i + 1), E[i + 1], q1);
        q2 = fmaf(__shfl(v, src0 + i + 2), E[i + 2], q2);
      }
      float vn = (q0 + q1 + q2) * ge;
      v = (act && mk) ? vn : v;
      if ((t & 7) == 0) {
        // renorm by power of 2 of group max (exact; C compensates)
        float m = v;
#pragma unroll
        for (int d = 16; d >= 1; d >>= 1) m = fmaxf(m, __shfl_xor(m, d));
        int ex = (int)((__float_as_uint(m) >> 23) & 255u) - 127;
        v *= __uint_as_float((unsigned)(127 - ex) << 23);
        C += (float)ex * 0.6931471805599453f;
      }
    }
    float wv = act ? v * __expf(ev[jj]) : 0.f;
#pragma unroll
    for (int d = 16; d >= 1; d >>= 1) wv += __shfl_xor(wv, d);
    if (j == 0) logZ[b] = C + __logf(wv);
  } else {
    // ---- Viterbi: 3 parallel argmax chains + tie-safe merge ----
    float Tc[TT];
#pragma unroll
    for (int i = 0; i < TT; ++i) Tc[i] = trans[i * TT + jj];
    float sc = act ? (sv[jj] + myE[jj]) : -3.0e38f;
    float e_nx = myE[TT + jj];
    int mk_nx = myM[1];
    for (int t = 1; t < SS; ++t) {
      const float e = e_nx;
      const int mk = mk_nx;
      const int tn = (t + 1 < SS) ? (t + 1) : (SS - 1);
      e_nx = myE[tn * TT + jj];
      mk_nx = myM[tn];
      float v0 = -3.0e38f, v1 = -3.0e38f, v2 = -3.0e38f;
      int i0 = 0, i1 = 0, i2 = 0;
#pragma unroll
      for (int i = 0; i < TT; i += 3) {
        float x0 = __shfl(sc, src0 + i) + Tc[i];
        float x1 = __shfl(sc, src0 + i + 1) + Tc[i + 1];
        float x2 = __shfl(sc, src0 + i + 2) + Tc[i + 2];
        if (x0 > v0) { v0 = x0; i0 = i; }
        if (x1 > v1) { v1 = x1; i1 = i + 1; }
        if (x2 > v2) { v2 = x2; i2 = i + 2; }
      }
      // merge with first-index tie-break (matches jnp.argmax)
      float best = v0;
      int bi = i0;
      if (v1 > best || (v1 == best && i1 < bi)) { best = v1; bi = i1; }
      if (v2 > best || (v2 == best && i2 < bi)) { best = v2; bi = i2; }
      float ns = best + e;
      sc = (act && mk) ? ns : sc;
      bp[g][t][j] = (unsigned char)(mk ? bi : j);
    }
    float fsv = act ? (sc + ev[jj]) : -3.0e38f;
    int idx = j;
#pragma unroll
    for (int d = 16; d >= 1; d >>= 1) {
      float ov = __shfl_xor(fsv, d);
      int oi = __shfl_xor(idx, d);
      bool take = (ov > fsv) || (ov == fsv && oi < idx);
      fsv = take ? ov : fsv;
      idx = take ? oi : idx;
    }
    __syncthreads();
    if (j == 0) {
      int tag = idx;
      sTag[g][SS - 1] = (unsigned char)tag;
      for (int t = SS - 1; t >= 1; --t) {
        tag = bp[g][t][tag];
        sTag[g][t - 1] = (unsigned char)tag;
      }
    }
    __syncthreads();
    // coalesced copy-out: pred = where(mask, tags, 0) as float
    for (int i = lane; i < 2 * SS; i += 64) {
      pred[(size_t)b0 * SS + i] = (float)(sM[i] ? (int)sTag[i >> 9][i & (SS - 1)] : 0);
    }
  }
}

// ---------------- Kernel 3: numerator + loss, one block per batch ----------------
__global__ __launch_bounds__(64, 1) void k_loss(const float* __restrict__ emis,
                                                const int* __restrict__ mask,
                                                const int* __restrict__ labels,
                                                const float* __restrict__ trans,
                                                const float* __restrict__ sv,
                                                const float* __restrict__ ev,
                                                const float* __restrict__ logZ,
                                                float* __restrict__ outv) {
  const int b = blockIdx.x;
  const int lane = threadIdx.x;
  float p = 0.f;
  int cnt = 0;
  for (int t = lane; t < SS; t += 64) {
    cnt += mask[b * SS + t] ? 1 : 0;
    if (t >= 1) {
      const int lp = labels[b * SS + t - 1];
      const int lc = labels[b * SS + t];
      const float mk = (float)mask[b * SS + t];
      p += mk * (trans[lp * TT + lc] + emis[((size_t)b * SS + t) * TT + lc]);
    }
  }
  p = wave_sum(p);
#pragma unroll
  for (int d = 32; d >= 1; d >>= 1) cnt += __shfl_xor(cnt, d);
  if (lane == 0) {
    const int l0 = labels[b * SS];
    float numer = p + sv[l0] + emis[(size_t)b * SS * TT + l0];
    numer += ev[labels[b * SS + cnt - 1]];
    atomicAdd(outv, logZ[b] - numer);  // loss = sum_b (logZ - numerator)
  }
}

extern "C" void kernel_launch(void* const* d_in, const int* in_sizes, int n_in,
                              void* d_out, int out_size, void* d_ws, size_t ws_size,
                              hipStream_t stream) {
  const float* hs = (const float*)d_in[0];
  const int* msk = (const int*)d_in[1];
  const int* lab = (const int*)d_in[2];
  const float* W = (const float*)d_in[3];
  const float* bias = (const float*)d_in[4];
  const float* trans = (const float*)d_in[5];
  const float* sv = (const float*)d_in[6];
  const float* ev = (const float*)d_in[7];
  float* out = (float*)d_out;

  float* emis = (float*)d_ws;                 // 64*512*21 floats
  float* logZ = emis + (size_t)BB * SS * TT;  // 64 floats

  hipMemsetAsync(d_out, 0, 4, stream);  // zero the loss accumulator
  k_emis<<<512, 512, 0, stream>>>(hs, W, bias, emis);
  k_scan<<<64, 64, 0, stream>>>(emis, msk, trans, sv, ev, logZ, out + 1);
  k_loss<<<64, 64, 0, stream>>>(emis, msk, lab, trans, sv, ev, logZ, out);
}

// Round 7
// 464.636 us; speedup vs baseline: 2.8019x; 1.0201x over previous
//
#include <hip/hip_runtime.h>
#include <math.h>
#include <stdint.h>

#define BB 64
#define SS 512
#define HH 1024
#define TT 21

// DPP-based partial reduce within row of 16, then cross-row shuffles.
template <int CTRL>
__device__ __forceinline__ float dpp_add(float v) {
  int t = __builtin_amdgcn_update_dpp(0, __float_as_int(v), CTRL, 0xF, 0xF, true);
  return v + __int_as_float(t);
}
__device__ __forceinline__ float wave_sum(float v) {
  v = dpp_add<0x121>(v);  // row_ror:1
  v = dpp_add<0x122>(v);  // row_ror:2
  v = dpp_add<0x124>(v);  // row_ror:4
  v = dpp_add<0x128>(v);  // row_ror:8
  v += __shfl_xor(v, 16);
  v += __shfl_xor(v, 32);
  return v;
}

#define DOT4(A, H, WV)    \
  A = fmaf(H.x, WV.x, A); \
  A = fmaf(H.y, WV.y, A); \
  A = fmaf(H.z, WV.z, A); \
  A = fmaf(H.w, WV.w, A)

// ---------------- Kernel 1: emissions = hs @ W^T + bias ----------------
// (unchanged from round 6 — scalar accumulators, no spills)
__global__ __launch_bounds__(512, 2) void k_emis(const float* __restrict__ hs,
                                                 const float* __restrict__ W,
                                                 const float* __restrict__ bias,
                                                 float* __restrict__ emis) {
  __shared__ float sW[TT * HH];  // 84 KiB
  __shared__ float sB[TT];
  {
    const float4* Wv = (const float4*)W;
    float4* sWv = (float4*)sW;
    for (int i = threadIdx.x; i < TT * HH / 4; i += 512) sWv[i] = Wv[i];
    if (threadIdx.x < TT) sB[threadIdx.x] = bias[threadIdx.x];
  }
  __syncthreads();
  const int lane = threadIdx.x & 63;
  const int wid = threadIdx.x >> 6;     // 0..7
  const int gw = blockIdx.x * 8 + wid;  // 0..4095 waves, 8 rows each
  for (int g = 0; g < 4; ++g) {
    const int row0 = gw * 8 + g * 2;
    const float4* hp0 = (const float4*)(hs + (size_t)row0 * HH);
    const float4* hp1 = (const float4*)(hs + (size_t)(row0 + 1) * HH);
    float4 h0[4], h1[4];
#pragma unroll
    for (int c = 0; c < 4; ++c) {
      h0[c] = hp0[c * 64 + lane];
      h1[c] = hp1[c * 64 + lane];
    }
    float* ep0 = emis + (size_t)row0 * TT;
    float* ep1 = ep0 + TT;
#pragma unroll 1
    for (int tg = 0; tg < TT; tg += 3) {
      float a00 = 0.f, a01 = 0.f, a02 = 0.f;
      float a10 = 0.f, a11 = 0.f, a12 = 0.f;
#pragma unroll
      for (int c = 0; c < 4; ++c) {
        float4 w0 = ((const float4*)(sW + (tg + 0) * HH))[c * 64 + lane];
        float4 w1 = ((const float4*)(sW + (tg + 1) * HH))[c * 64 + lane];
        float4 w2 = ((const float4*)(sW + (tg + 2) * HH))[c * 64 + lane];
        DOT4(a00, h0[c], w0);
        DOT4(a01, h0[c], w1);
        DOT4(a02, h0[c], w2);
        DOT4(a10, h1[c], w0);
        DOT4(a11, h1[c], w1);
        DOT4(a12, h1[c], w2);
      }
      a00 = wave_sum(a00);
      a01 = wave_sum(a01);
      a02 = wave_sum(a02);
      a10 = wave_sum(a10);
      a11 = wave_sum(a11);
      a12 = wave_sum(a12);
      if (lane == 0) {
        ep0[tg] = a00 + sB[tg];
        ep0[tg + 1] = a01 + sB[tg + 1];
        ep0[tg + 2] = a02 + sB[tg + 2];
      }
      if (lane == 1) {
        ep1[tg] = a10 + sB[tg];
        ep1[tg + 1] = a11 + sB[tg + 1];
        ep1[tg + 2] = a12 + sB[tg + 2];
      }
    }
  }
}

// ---------------- Kernel 2: CRF forward scan + Viterbi ----------------
// Round-6 lesson: 21 ds_bpermute per step pay DS latency repeatedly
// (~1150 cyc/iter). New: broadcast via LDS — one ds_write_b32 of v/sc,
// then 6 ds_read_b128 deliver the whole 21-vector into registers with
// compile-time component indexing; DS latency paid once (~120 cyc).
// Renorm max is now an in-register v_max3 tree (no shuffles); the scale
// is an exact power of 2 applied to BOTH v and q -> numerics unchanged.
__global__ __launch_bounds__(64, 1) void k_scan(const float* __restrict__ emis,
                                                const int* __restrict__ mask,
                                                const float* __restrict__ trans,
                                                const float* __restrict__ sv,
                                                const float* __restrict__ ev,
                                                float* __restrict__ logZ,
                                                float* __restrict__ pred) {
  __shared__ float sE[2 * SS * TT];        // 84 KiB
  __shared__ int sM[2 * SS];               // 4 KiB
  __shared__ unsigned char bp[2][SS][32];  // 32 KiB (viterbi only)
  __shared__ unsigned char sTag[2][SS];    // 1 KiB  (viterbi only)
  __shared__ float sV[2][24];              // broadcast buffer
  const int lane = threadIdx.x;
  const int g = lane >> 5;
  const int j = lane & 31;
  const bool act = (j < TT);
  const int jj = act ? j : 0;
  const int b0 = (blockIdx.x & 31) * 2;
  const int b = b0 + g;

  if (lane < 48) ((float*)sV)[lane] = 0.f;  // zero incl. pad entries 21..23

  // ---- stage emissions + mask for both batches of this block ----
  {
    const float4* src = (const float4*)(emis + (size_t)b0 * SS * TT);
    float4* dst = (float4*)sE;
    for (int i = lane; i < 2 * SS * TT / 4; i += 64) dst[i] = src[i];
    const int* msrc = mask + b0 * SS;
    for (int i = lane; i < 2 * SS; i += 64) sM[i] = msrc[i];
  }
  __syncthreads();
  const float* myE = sE + g * SS * TT;
  const int* myM = sM + g * SS;

  if (blockIdx.x < 32) {
    // ---- CRF logsumexp scan (exp domain, v = exp(alpha - C)) ----
    float E[TT];
#pragma unroll
    for (int i = 0; i < TT; ++i) E[i] = __expf(trans[i * TT + jj]);
    float v = act ? __expf(sv[jj] + myE[jj]) : 0.f;
    float C = 0.f;
    float ge_nx = __expf(myE[TT + jj]);
    int mk_nx = myM[1];
    for (int t = 1; t < SS; ++t) {
      const float ge = ge_nx;
      const int mk = mk_nx;
      const int tn = (t + 1 < SS) ? (t + 1) : (SS - 1);
      ge_nx = __expf(myE[tn * TT + jj]);
      mk_nx = myM[tn];
      if (act) sV[g][j] = v;
      __syncthreads();  // single wave: cheap; orders write->reads
      const float4* vb = (const float4*)sV[g];
      float4 V0 = vb[0], V1 = vb[1], V2 = vb[2], V3 = vb[3], V4 = vb[4], V5 = vb[5];
      float scale = 1.0f;
      if ((t & 7) == 0) {
        // renorm: max of all 21 v's (in registers, uniform across lanes)
        float m = fmaxf(fmaxf(fmaxf(V0.x, V0.y), fmaxf(V0.z, V0.w)),
                        fmaxf(fmaxf(V1.x, V1.y), fmaxf(V1.z, V1.w)));
        m = fmaxf(m, fmaxf(fmaxf(V2.x, V2.y), fmaxf(V2.z, V2.w)));
        m = fmaxf(m, fmaxf(fmaxf(V3.x, V3.y), fmaxf(V3.z, V3.w)));
        m = fmaxf(m, fmaxf(fmaxf(V4.x, V4.y), fmaxf(V4.z, V4.w)));
        m = fmaxf(m, V5.x);
        int ex = (int)((__float_as_uint(m) >> 23) & 255u) - 127;
        scale = __uint_as_float((unsigned)(127 - ex) << 23);  // 2^-ex exact
        C += (float)ex * 0.6931471805599453f;
        v *= scale;  // keep masked lanes consistent with C
      }
      // q chains: identical summation order to the verified round-6 kernel
      float q0 = V0.x * E[0], q1 = V0.y * E[1], q2 = V0.z * E[2];
      q0 = fmaf(V0.w, E[3], q0);  q1 = fmaf(V1.x, E[4], q1);  q2 = fmaf(V1.y, E[5], q2);
      q0 = fmaf(V1.z, E[6], q0);  q1 = fmaf(V1.w, E[7], q1);  q2 = fmaf(V2.x, E[8], q2);
      q0 = fmaf(V2.y, E[9], q0);  q1 = fmaf(V2.z, E[10], q1); q2 = fmaf(V2.w, E[11], q2);
      q0 = fmaf(V3.x, E[12], q0); q1 = fmaf(V3.y, E[13], q1); q2 = fmaf(V3.z, E[14], q2);
      q0 = fmaf(V3.w, E[15], q0); q1 = fmaf(V4.x, E[16], q1); q2 = fmaf(V4.y, E[17], q2);
      q0 = fmaf(V4.z, E[18], q0); q1 = fmaf(V4.w, E[19], q1); q2 = fmaf(V5.x, E[20], q2);
      float vn = ((q0 + q1 + q2) * scale) * ge;
      v = (act && mk) ? vn : v;
    }
    float wv = act ? v * __expf(ev[jj]) : 0.f;
#pragma unroll
    for (int d = 16; d >= 1; d >>= 1) wv += __shfl_xor(wv, d);
    if (j == 0) logZ[b] = C + __logf(wv);
  } else {
    // ---- Viterbi: LDS broadcast + 3 argmax chains + tie-safe merge ----
    float Tc[TT];
#pragma unroll
    for (int i = 0; i < TT; ++i) Tc[i] = trans[i * TT + jj];
    float sc = act ? (sv[jj] + myE[jj]) : -3.0e38f;
    float e_nx = myE[TT + jj];
    int mk_nx = myM[1];
    for (int t = 1; t < SS; ++t) {
      const float e = e_nx;
      const int mk = mk_nx;
      const int tn = (t + 1 < SS) ? (t + 1) : (SS - 1);
      e_nx = myE[tn * TT + jj];
      mk_nx = myM[tn];
      if (act) sV[g][j] = sc;
      __syncthreads();
      const float4* vb = (const float4*)sV[g];
      float4 V0 = vb[0], V1 = vb[1], V2 = vb[2], V3 = vb[3], V4 = vb[4], V5 = vb[5];
      float b0v, b1v, b2v;
      int i0, i1, i2;
#define ARGSTEP(BV, BI, VAL, IDX)          \
  {                                        \
    float x_ = (VAL) + Tc[IDX];            \
    if (x_ > BV) { BV = x_; BI = (IDX); }  \
  }
      b0v = V0.x + Tc[0]; i0 = 0;
      b1v = V0.y + Tc[1]; i1 = 1;
      b2v = V0.z + Tc[2]; i2 = 2;
      ARGSTEP(b0v, i0, V0.w, 3);  ARGSTEP(b1v, i1, V1.x, 4);  ARGSTEP(b2v, i2, V1.y, 5);
      ARGSTEP(b0v, i0, V1.z, 6);  ARGSTEP(b1v, i1, V1.w, 7);  ARGSTEP(b2v, i2, V2.x, 8);
      ARGSTEP(b0v, i0, V2.y, 9);  ARGSTEP(b1v, i1, V2.z, 10); ARGSTEP(b2v, i2, V2.w, 11);
      ARGSTEP(b0v, i0, V3.x, 12); ARGSTEP(b1v, i1, V3.y, 13); ARGSTEP(b2v, i2, V3.z, 14);
      ARGSTEP(b0v, i0, V3.w, 15); ARGSTEP(b1v, i1, V4.x, 16); ARGSTEP(b2v, i2, V4.y, 17);
      ARGSTEP(b0v, i0, V4.z, 18); ARGSTEP(b1v, i1, V4.w, 19); ARGSTEP(b2v, i2, V5.x, 20);
#undef ARGSTEP
      // merge with first-index tie-break (matches jnp.argmax)
      float best = b0v;
      int bi = i0;
      if (b1v > best || (b1v == best && i1 < bi)) { best = b1v; bi = i1; }
      if (b2v > best || (b2v == best && i2 < bi)) { best = b2v; bi = i2; }
      float ns = best + e;
      sc = (act && mk) ? ns : sc;
      bp[g][t][j] = (unsigned char)(mk ? bi : j);
    }
    float fsv = act ? (sc + ev[jj]) : -3.0e38f;
    int idx = j;
#pragma unroll
    for (int d = 16; d >= 1; d >>= 1) {
      float ov = __shfl_xor(fsv, d);
      int oi = __shfl_xor(idx, d);
      bool take = (ov > fsv) || (ov == fsv && oi < idx);
      fsv = take ? ov : fsv;
      idx = take ? oi : idx;
    }
    __syncthreads();
    if (j == 0) {
      int tag = idx;
      sTag[g][SS - 1] = (unsigned char)tag;
      for (int t = SS - 1; t >= 1; --t) {
        tag = bp[g][t][tag];
        sTag[g][t - 1] = (unsigned char)tag;
      }
    }
    __syncthreads();
    // coalesced copy-out: pred = where(mask, tags, 0) as float
    for (int i = lane; i < 2 * SS; i += 64) {
      pred[(size_t)b0 * SS + i] = (float)(sM[i] ? (int)sTag[i >> 9][i & (SS - 1)] : 0);
    }
  }
}

// ---------------- Kernel 3: numerator + loss, one block per batch ----------------
__global__ __launch_bounds__(64, 1) void k_loss(const float* __restrict__ emis,
                                                const int* __restrict__ mask,
                                                const int* __restrict__ labels,
                                                const float* __restrict__ trans,
                                                const float* __restrict__ sv,
                                                const float* __restrict__ ev,
                                                const float* __restrict__ logZ,
                                                float* __restrict__ outv) {
  const int b = blockIdx.x;
  const int lane = threadIdx.x;
  float p = 0.f;
  int cnt = 0;
  for (int t = lane; t < SS; t += 64) {
    cnt += mask[b * SS + t] ? 1 : 0;
    if (t >= 1) {
      const int lp = labels[b * SS + t - 1];
      const int lc = labels[b * SS + t];
      const float mk = (float)mask[b * SS + t];
      p += mk * (trans[lp * TT + lc] + emis[((size_t)b * SS + t) * TT + lc]);
    }
  }
  p = wave_sum(p);
#pragma unroll
  for (int d = 32; d >= 1; d >>= 1) cnt += __shfl_xor(cnt, d);
  if (lane == 0) {
    const int l0 = labels[b * SS];
    float numer = p + sv[l0] + emis[(size_t)b * SS * TT + l0];
    numer += ev[labels[b * SS + cnt - 1]];
    atomicAdd(outv, logZ[b] - numer);  // loss = sum_b (logZ - numerator)
  }
}

extern "C" void kernel_launch(void* const* d_in, const int* in_sizes, int n_in,
                              void* d_out, int out_size, void* d_ws, size_t ws_size,
                              hipStream_t stream) {
  const float* hs = (const float*)d_in[0];
  const int* msk = (const int*)d_in[1];
  const int* lab = (const int*)d_in[2];
  const float* W = (const float*)d_in[3];
  const float* bias = (const float*)d_in[4];
  const float* trans = (const float*)d_in[5];
  const float* sv = (const float*)d_in[6];
  const float* ev = (const float*)d_in[7];
  float* out = (float*)d_out;

  float* emis = (float*)d_ws;                 // 64*512*21 floats
  float* logZ = emis + (size_t)BB * SS * TT;  // 64 floats

  hipMemsetAsync(d_out, 0, 4, stream);  // zero the loss accumulator
  k_emis<<<512, 512, 0, stream>>>(hs, W, bias, emis);
  k_scan<<<64, 64, 0, stream>>>(emis, msk, trans, sv, ev, logZ, out + 1);
  k_loss<<<64, 64, 0, stream>>>(emis, msk, lab, trans, sv, ev, logZ, out);
}